// Round 7
// baseline (110.522 us; speedup 1.0000x reference)
//
#include <hip/hip_runtime.h>
#include <hip/hip_bf16.h>

// input_data:       (B=16, S=4096, C=256) fp32
// shifting_weights: (B=16, D=1024)        fp32
// output:           (B=16, D=1024, C=256) fp32
// out[b,d,c] = sum_s exp(-((s+1) - ((d+1)+w[b,d])*4)^2) / AMP * input[b,s,c]
//
// R7 = R6 + non-temporal cache policy on all global traffic.
// Surviving theory after R1-R6: kernel time (~27-30 us vs 13.3 us compulsory)
// is the DIRTY-POISON WRITEBACK floor -- the harness's 285 MB 0xAA poison
// fills leave L2+L3 full of dirty lines; every line the kernel allocates
// evicts one -> ~84 MB of writeback during the kernel window. 67+17+84 =
// 168 MB ~= 27 us at 6.3 TB/s = observed, invariant to structure.
// Fix attempt: nt (CPol bit1, aux=2) on the global_load_lds staging DMA and
// the rare fallback loads -> if nt skips L2/L3 allocation, no evictions, no
// writeback. Paired with R6's LDS dedup so the lost cache reuse doesn't cost
// extra HBM reads. NT stores already in place.

constexpr int B = 16;
constexpr int S = 4096;
constexpr int C = 256;
constexpr int D = 1024;
constexpr float SCALING = (float)S / (float)D;   // 4.0
constexpr float INV_AMP = 1.0f / 1.772637204826652f;
constexpr int RAD   = 8;
constexpr int TAPS  = 2 * RAD + 1;   // 17
constexpr int GB    = 8;             // d's per block (1 per wave)
constexpr int WPB   = 8;             // waves per block
constexpr int HROWS = 64;            // staged rows -> 64 KB LDS
constexpr int NUM_XCD = 8;

typedef float f32x4 __attribute__((ext_vector_type(4)));

__device__ __forceinline__ void stage_row16_nt(const float* g, float* l) {
    // width=16 DMA; aux=2 -> CPol "nt" on gfx950 (non-temporal / no-allocate).
    __builtin_amdgcn_global_load_lds(
        (const __attribute__((address_space(1))) void*)g,
        (__attribute__((address_space(3))) void*)l,
        16, 0, 2);
}

__global__ __launch_bounds__(512) void shifting_kernel(
    const float* __restrict__ input,
    const float* __restrict__ wts,
    float* __restrict__ out)
{
    __shared__ float buf[HROWS * C];   // 64 KB, row r at buf + r*256

    const int wave = threadIdx.x >> 6;
    const int lane = threadIdx.x & 63;

    // XCD-contiguity swizzle (kept; proven +6.5 us in R3).
    const int per_xcd = gridDim.x >> 3;              // 2048/8 = 256
    const int pblk = blockIdx.x;
    const int lblk = (pblk & (NUM_XCD - 1)) * per_xcd + (pblk >> 3);

    const int gidx0 = lblk * GB;                     // first flat b*D+d
    const int b     = gidx0 >> 10;                   // / D
    const int d0    = gidx0 & (D - 1);               // aligned: all 8 same b

    float cmin = 1e30f, cmax = -1e30f, cme = 0.0f;
#pragma unroll
    for (int i = 0; i < GB; ++i) {
        float ci = ((float)(d0 + i + 1) + wts[gidx0 + i]) * SCALING;
        cmin = fminf(cmin, ci);
        cmax = fmaxf(cmax, ci);
        cme  = (i == wave) ? ci : cme;
    }

    const int lo = max(1, (int)rintf(cmin) - RAD);
    const int hi = min(S, (int)rintf(cmax) + RAD);
    const unsigned cstage = (unsigned)max(min(hi - lo + 1, HROWS), 0);

    // ---- Stage union window rows [lo, lo+cstage-1], wave-interleaved ----
    const float* stage_g = input + (size_t)b * S * C
                                 + (size_t)(lo - 1) * C + (lane << 2);
    for (int r = wave; r < (int)cstage; r += WPB)
        stage_row16_nt(stage_g + (size_t)r * C, buf + r * C);

    __syncthreads();   // drains vmcnt -> staged data visible

    // ---- Compute: this wave's 17 taps ----
    const float c  = cme;
    const int   s0 = (int)rintf(c) - RAD;
    const float* rb = input + (size_t)b * S * C + (lane << 2);

    f32x4 acc = {0.f, 0.f, 0.f, 0.f};
#pragma unroll
    for (int k = 0; k < TAPS; ++k) {
        int s = s0 + k;
        float dd = (float)s - c;
        float g  = __expf(-dd * dd);
        unsigned u = (unsigned)(s - lo);   // wraps for s < lo -> global path
        f32x4 v;
        if (u < cstage) {                  // wave-uniform branch
            v = *(const f32x4*)(buf + (size_t)u * C + (lane << 2));
        } else {
            int sc = min(max(s, 1), S);
            v = __builtin_nontemporal_load(
                    (const f32x4*)(rb + (size_t)(sc - 1) * C));
            g = (s >= 1 && s <= S) ? g : 0.0f;   // exact: excluded taps are 0
        }
        acc += g * v;
    }

    f32x4 r = acc * INV_AMP;
    __builtin_nontemporal_store(
        r, (f32x4*)(out + (size_t)(gidx0 + wave) * C + (lane << 2)));
}

extern "C" void kernel_launch(void* const* d_in, const int* in_sizes, int n_in,
                              void* d_out, int out_size, void* d_ws, size_t ws_size,
                              hipStream_t stream) {
    const float* input = (const float*)d_in[0];
    const float* wts   = (const float*)d_in[1];
    float* out         = (float*)d_out;

    dim3 grid(B * D / GB);   // 2048 blocks: 8 waves/block, 1 d per wave
    dim3 block(WPB * 64);    // 512 threads
    shifting_kernel<<<grid, block, 0, stream>>>(input, wts, out);
}

// Round 8
// 97.611 us; speedup vs baseline: 1.1323x; 1.1323x over previous
//
#include <hip/hip_runtime.h>
#include <hip/hip_bf16.h>

// input_data:       (B=16, S=4096, C=256) fp32
// shifting_weights: (B=16, D=1024)        fp32
// output:           (B=16, D=1024, C=256) fp32
// out[b,d,c] = sum_s exp(-((s+1) - ((d+1)+w[b,d])*4)^2) / AMP * input[b,s,c]
// Gaussian width 1: 17-tap window centered at round(center); taps beyond
// |diff| > 8.5 are < 4e-32.
//
// R8 = revert to R3 (best of 7 variants, 97.3 us).
// Final model (R1-R7 evidence): kernel term ~14-17 us ~= compulsory HBM floor
// (67 MB input read-once + 17 MB output write-once = 84 MB / 6.3 TB/s =
// 13.3 us); the rest of dur_us is fixed harness restore/poison work.
//  - 1 d per wave, fixed 17 fully-unrolled independent loads (MLP).
//  - 16384 waves = 32/CU demand (TLP).
//  - XCD-contiguous block swizzle: contiguous d-span per XCD so the ~50%
//    window overlap between neighboring blocks hits the XCD's own L2
//    (proven +6.5 us vs no swizzle in R2->R3; nt no-allocate loses it, R7).
//  - Non-temporal stores: write-once output doesn't evict cached input.

constexpr int B = 16;
constexpr int S = 4096;
constexpr int C = 256;
constexpr int D = 1024;
constexpr float SCALING = (float)S / (float)D;   // 4.0
constexpr float INV_AMP = 1.0f / 1.772637204826652f;
constexpr int RAD  = 8;
constexpr int TAPS = 2 * RAD + 1;                // 17
constexpr int NUM_XCD = 8;

typedef float f32x4 __attribute__((ext_vector_type(4)));

__global__ __launch_bounds__(256) void shifting_kernel(
    const float* __restrict__ input,
    const float* __restrict__ wts,
    float* __restrict__ out)
{
    const int wave = threadIdx.x >> 6;
    const int lane = threadIdx.x & 63;

    // XCD-contiguity swizzle (bijection on [0, gridDim.x)):
    // physical block p runs on XCD (p % 8); give XCD x the logical range
    // [x*per_xcd, (x+1)*per_xcd) so its L2 sees a contiguous d-span.
    const int per_xcd = gridDim.x >> 3;              // 4096/8 = 512
    const int pblk = blockIdx.x;
    const int lblk = (pblk & (NUM_XCD - 1)) * per_xcd + (pblk >> 3);

    const int gidx = (lblk << 2) + wave;             // flat b*D + d
    const int b    = gidx >> 10;                     // / D
    const int d    = gidx & (D - 1);

    const float w = wts[gidx];
    const float c = ((float)(d + 1) + w) * SCALING;
    const int s_mid = (int)rintf(c);
    const int s0    = s_mid - RAD;                   // first tap (1-based s)

    const float* rowbase = input + ((size_t)b * S * C) + (lane << 2);

    f32x4 acc = {0.f, 0.f, 0.f, 0.f};

    if (s0 >= 1 && s0 + TAPS - 1 <= S) {
        // Interior fast path: 17 independent 1 KB wave-loads.
        const float* p = rowbase + (size_t)(s0 - 1) * C;
#pragma unroll
        for (int k = 0; k < TAPS; ++k) {
            f32x4 v = *(const f32x4*)(p + (size_t)k * C);
            float diff = (float)(s0 + k) - c;
            float g = __expf(-diff * diff) * INV_AMP;
            acc += g * v;
        }
    } else {
        // Edge path (rare): clamp address, zero out-of-range weights.
#pragma unroll
        for (int k = 0; k < TAPS; ++k) {
            int s  = s0 + k;
            int sc = min(max(s, 1), S);
            f32x4 v = *(const f32x4*)(rowbase + (size_t)(sc - 1) * C);
            float diff = (float)s - c;
            float g = __expf(-diff * diff) * INV_AMP;
            g = (s >= 1 && s <= S) ? g : 0.0f;
            acc += g * v;
        }
    }

    // Write-once output: non-temporal so it doesn't evict cached input.
    f32x4* outp = (f32x4*)(out + (size_t)gidx * C + (lane << 2));
    __builtin_nontemporal_store(acc, outp);
}

extern "C" void kernel_launch(void* const* d_in, const int* in_sizes, int n_in,
                              void* d_out, int out_size, void* d_ws, size_t ws_size,
                              hipStream_t stream) {
    const float* input = (const float*)d_in[0];
    const float* wts   = (const float*)d_in[1];
    float* out         = (float*)d_out;

    dim3 grid(B * D / 4);   // 4096 blocks, 4 waves/block, 1 d per wave
    dim3 block(256);
    shifting_kernel<<<grid, block, 0, stream>>>(input, wts, out);
}